// Round 1
// baseline (481.530 us; speedup 1.0000x reference)
//
#include <hip/hip_runtime.h>
#include <cstdint>
#include <cstddef>

// Problem constants (match reference setup_inputs)
#define B_ 4
#define N_ 500
#define C_ 256
#define NH_ 8
#define DH_ 32
#define P_ 32
#define G_ 4
#define CG_ 64
#define BN_ (B_*N_)

// feature level dims
__constant__ const int LVL_W[4] = {128, 64, 32, 16};

// ---------------------------------------------------------------------------
// K0: transpose (B,C,H,W) -> (B,H*W,C) for coalesced channel-group gathers
// block = 256 threads, tile = 64 pixels x 64 channels
__global__ __launch_bounds__(256) void transpose_feat(const float* __restrict__ src,
                                                      float* __restrict__ dst, int npix) {
  __shared__ float tile[64][65];
  int b = blockIdx.z;
  int c0 = blockIdx.y * 64;
  int p0 = blockIdx.x * 64;
  int t = threadIdx.x;
  for (int i = 0; i < 16; i++) {
    int cl = i * 4 + (t >> 6);
    int pl = t & 63;
    tile[cl][pl] = src[((size_t)b * C_ + (c0 + cl)) * npix + (p0 + pl)];
  }
  __syncthreads();
  for (int i = 0; i < 16; i++) {
    int pl = i * 4 + (t >> 6);
    int cl = t & 63;
    dst[((size_t)b * npix + (p0 + pl)) * C_ + (c0 + cl)] = tile[cl][pl];
  }
}

// ---------------------------------------------------------------------------
// K1: per-query prep: positional embedding + x = content + pe, box decode
// grid = BN_ blocks, 256 threads
__global__ __launch_bounds__(256) void prep_kernel(const float* __restrict__ qcontent,
                                                   const float* __restrict__ qbox,
                                                   float* __restrict__ x,
                                                   float* __restrict__ boxd) {
  int bn = blockIdx.x;
  int t = threadIdx.x;
  const float* qb = qbox + (size_t)bn * 4;
  float cx = qb[0], cy = qb[1], z = qb[2], r = qb[3];

  // pe channel t: d = t/64, j = (t%64)/2, sin if even / cos if odd
  int d = t >> 6;
  int j = (t >> 1) & 31;
  float token = (d == 0) ? cx * 0.001f : (d == 1) ? cy * 0.001f : (d == 2) ? z : r;
  // dim_t = 10000^(j/32) -> exp2(j * log2(10000)/32)
  float tj = exp2f((float)j * 0.41524136f); // log2(10000)/32 = 0.415241363...
  float val = token / tj;
  float pe = (t & 1) ? cosf(val) : sinf(val);
  x[(size_t)bn * C_ + t] = qcontent[(size_t)bn * C_ + t] + pe;

  if (t == 0) {
    float scale = exp2f(z);
    float w = scale * exp2f(-0.5f * r);
    float h = scale * exp2f(0.5f * r);
    float* bd = boxd + (size_t)bn * 12;
    float x1 = cx - 0.5f * w, y1 = cy - 0.5f * h, x2 = cx + 0.5f * w, y2 = cy + 0.5f * h;
    bd[0] = x1; bd[1] = y1; bd[2] = x2; bd[3] = y2;
    bd[4] = cx; bd[5] = cy; bd[6] = w; bd[7] = h; bd[8] = z;
    float area = fmaxf(x2 - x1, 0.f) * fmaxf(y2 - y1, 0.f);
    bd[9] = fmaxf(area, 1e-7f);
  }
}

// ---------------------------------------------------------------------------
// K2: QKV projections. 8 queries per block for W reuse.
#define QKV_QI 8
__global__ __launch_bounds__(256) void qkv_kernel(const float* __restrict__ x,
    const float* __restrict__ Wq, const float* __restrict__ bq,
    const float* __restrict__ Wk, const float* __restrict__ bk,
    const float* __restrict__ Wv, const float* __restrict__ bv,
    float* __restrict__ q, float* __restrict__ kT, float* __restrict__ vT) {
  __shared__ float xs[QKV_QI][C_];
  int blk = blockIdx.x;
  int t = threadIdx.x;
  int bn0 = blk * QKV_QI;
  for (int i = 0; i < QKV_QI; i++) xs[i][t] = x[(size_t)(bn0 + i) * C_ + t];
  __syncthreads();
  float accq[QKV_QI], acck[QKV_QI], accv[QKV_QI];
  for (int i = 0; i < QKV_QI; i++) { accq[i] = 0.f; acck[i] = 0.f; accv[i] = 0.f; }
  const float4* wq4 = (const float4*)(Wq + (size_t)t * C_);
  const float4* wk4 = (const float4*)(Wk + (size_t)t * C_);
  const float4* wv4 = (const float4*)(Wv + (size_t)t * C_);
  for (int k4 = 0; k4 < C_ / 4; k4++) {
    float4 wq = wq4[k4], wk = wk4[k4], wv = wv4[k4];
    for (int i = 0; i < QKV_QI; i++) {
      float4 xv = *(const float4*)&xs[i][k4 * 4];
      accq[i] += xv.x * wq.x + xv.y * wq.y + xv.z * wq.z + xv.w * wq.w;
      acck[i] += xv.x * wk.x + xv.y * wk.y + xv.z * wk.z + xv.w * wk.w;
      accv[i] += xv.x * wv.x + xv.y * wv.y + xv.z * wv.z + xv.w * wv.w;
    }
  }
  for (int i = 0; i < QKV_QI; i++) {
    int bn = bn0 + i;
    int b = bn / N_;
    int n = bn % N_;
    q[(size_t)bn * C_ + t] = accq[i] + bq[t];
    kT[((size_t)b * C_ + t) * N_ + n] = acck[i] + bk[t];
    vT[((size_t)b * C_ + t) * N_ + n] = accv[i] + bv[t];
  }
}

// ---------------------------------------------------------------------------
// K3: attention with IoF bias. 2 queries per block (LDS 38KB).
#define ATT_QI 2
__global__ __launch_bounds__(256) void attn_kernel(
    const float* __restrict__ q, const float* __restrict__ kT, const float* __restrict__ vT,
    const float* __restrict__ boxd, const float* __restrict__ tau_p,
    float* __restrict__ ctx) {
  __shared__ float p[ATT_QI][NH_][N_];
  __shared__ float bias[ATT_QI][N_];
  __shared__ float qs[ATT_QI][C_];
  __shared__ float red[ATT_QI * NH_];
  int blk = blockIdx.x;
  int b = blk / (N_ / ATT_QI);
  int n0 = (blk % (N_ / ATT_QI)) * ATT_QI;
  int t = threadIdx.x;
  for (int i = 0; i < ATT_QI; i++) qs[i][t] = q[((size_t)b * N_ + n0 + i) * C_ + t];
  for (int i = 0; i < ATT_QI; i++) {
    const float* bdn = boxd + ((size_t)b * N_ + n0 + i) * 12;
    float nx1 = bdn[0], ny1 = bdn[1], nx2 = bdn[2], ny2 = bdn[3];
    float inv_area = 1.0f / bdn[9];
    for (int m = t; m < N_; m += 256) {
      const float* bdm = boxd + ((size_t)b * N_ + m) * 12;
      float iw = fmaxf(fminf(nx2, bdm[2]) - fmaxf(nx1, bdm[0]), 0.f);
      float ih = fmaxf(fminf(ny2, bdm[3]) - fmaxf(ny1, bdm[1]), 0.f);
      bias[i][m] = logf(iw * ih * inv_area + 1e-7f);
    }
  }
  __syncthreads();
  const float scl = 0.17677669529663687f; // 32^-0.5
  for (int h = 0; h < NH_; h++) {
    float tau = tau_p[h];
    for (int mb = 0; mb < N_; mb += 256) {
      int m = mb + t;
      if (m < N_) {
        const float* kcol = kT + ((size_t)b * C_ + h * DH_) * N_ + m;
        float s0 = 0.f, s1 = 0.f;
        for (int d = 0; d < DH_; d++) {
          float kv = kcol[(size_t)d * N_];
          s0 += qs[0][h * DH_ + d] * kv;
          s1 += qs[1][h * DH_ + d] * kv;
        }
        p[0][h][m] = s0 * scl + bias[0][m] * tau;
        p[1][h][m] = s1 * scl + bias[1][m] * tau;
      }
    }
  }
  __syncthreads();
  {
    // softmax: 16 (qi,h) pairs, 16 threads per pair
    int pair = t >> 4;
    int j = t & 15;
    int qi = pair >> 3;
    int h = pair & 7;
    float mx = -1e30f;
    for (int m = j; m < N_; m += 16) mx = fmaxf(mx, p[qi][h][m]);
    for (int off = 8; off >= 1; off >>= 1) mx = fmaxf(mx, __shfl_xor(mx, off, 64));
    float sum = 0.f;
    for (int m = j; m < N_; m += 16) {
      float e = __expf(p[qi][h][m] - mx);
      p[qi][h][m] = e;
      sum += e;
    }
    for (int off = 8; off >= 1; off >>= 1) sum += __shfl_xor(sum, off, 64);
    if (j == 0) red[pair] = 1.0f / sum;
  }
  __syncthreads();
  {
    int h = t >> 5;
    int d = t & 31;
    const float* vrow = vT + ((size_t)b * C_ + h * DH_ + d) * N_;
    float a0 = 0.f, a1 = 0.f;
    for (int m = 0; m < N_; m++) {
      float vv = vrow[m];
      a0 += p[0][h][m] * vv;
      a1 += p[1][h][m] * vv;
    }
    ctx[((size_t)b * N_ + n0 + 0) * C_ + t] = a0 * red[0 * 8 + h];
    ctx[((size_t)b * N_ + n0 + 1) * C_ + t] = a1 * red[1 * 8 + h];
  }
}

// ---------------------------------------------------------------------------
// K4: output projection + residual + layernorm. 4 queries per block.
#define PROJ_QI 4
__global__ __launch_bounds__(256) void projln_kernel(const float* __restrict__ ctx,
    const float* __restrict__ x,
    const float* __restrict__ Wo, const float* __restrict__ bo,
    const float* __restrict__ ln_g, const float* __restrict__ ln_b,
    float* __restrict__ qc_ws, float* __restrict__ qc_out) {
  __shared__ float cs[PROJ_QI][C_];
  __shared__ float redbuf[PROJ_QI][8];
  int blk = blockIdx.x;
  int t = threadIdx.x;
  int bn0 = blk * PROJ_QI;
  for (int i = 0; i < PROJ_QI; i++) cs[i][t] = ctx[(size_t)(bn0 + i) * C_ + t];
  __syncthreads();
  float acc[PROJ_QI] = {0.f, 0.f, 0.f, 0.f};
  const float4* w4 = (const float4*)(Wo + (size_t)t * C_);
  for (int k4 = 0; k4 < C_ / 4; k4++) {
    float4 w = w4[k4];
    for (int i = 0; i < PROJ_QI; i++) {
      float4 cv = *(const float4*)&cs[i][k4 * 4];
      acc[i] += cv.x * w.x + cv.y * w.y + cv.z * w.z + cv.w * w.w;
    }
  }
  float y[PROJ_QI];
  int wave = t >> 6, lane = t & 63;
  for (int i = 0; i < PROJ_QI; i++) {
    y[i] = x[(size_t)(bn0 + i) * C_ + t] + acc[i] + bo[t];
    float s1 = y[i], s2 = y[i] * y[i];
    for (int off = 32; off >= 1; off >>= 1) {
      s1 += __shfl_xor(s1, off, 64);
      s2 += __shfl_xor(s2, off, 64);
    }
    if (lane == 0) { redbuf[i][wave] = s1; redbuf[i][wave + 4] = s2; }
  }
  __syncthreads();
  for (int i = 0; i < PROJ_QI; i++) {
    float s1 = redbuf[i][0] + redbuf[i][1] + redbuf[i][2] + redbuf[i][3];
    float s2 = redbuf[i][4] + redbuf[i][5] + redbuf[i][6] + redbuf[i][7];
    float mu = s1 * (1.0f / C_);
    float var = s2 * (1.0f / C_) - mu * mu;
    float inv = rsqrtf(var + 1e-5f);
    float o = (y[i] - mu) * inv * ln_g[t] + ln_b[t];
    qc_ws[(size_t)(bn0 + i) * C_ + t] = o;
    qc_out[(size_t)(bn0 + i) * C_ + t] = o;
  }
}

// ---------------------------------------------------------------------------
// K5: offset/scale heads + sample_xy / sample_z / level softmax weights
#define HEAD_QI 4
__global__ __launch_bounds__(256) void head_kernel(const float* __restrict__ qc,
    const float* __restrict__ boxd,
    const float* __restrict__ offW, const float* __restrict__ offb,
    const float* __restrict__ scW, const float* __restrict__ scb,
    float* __restrict__ out_offset, float* __restrict__ out_sxy,
    float* __restrict__ out_sz, float* __restrict__ out_sl,
    float* __restrict__ sxy_ws, float* __restrict__ zw_ws) {
  __shared__ float qs[HEAD_QI][C_];
  int blk = blockIdx.x;
  int t = threadIdx.x;
  int bn0 = blk * HEAD_QI;
  for (int i = 0; i < HEAD_QI; i++) qs[i][t] = qc[(size_t)(bn0 + i) * C_ + t];
  __syncthreads();
  float acc[HEAD_QI] = {0.f, 0.f, 0.f, 0.f};
  const float4* w4 = (const float4*)(offW + (size_t)t * C_);
  for (int k4 = 0; k4 < C_ / 4; k4++) {
    float4 w = w4[k4];
    for (int i = 0; i < HEAD_QI; i++) {
      float4 cv = *(const float4*)&qs[i][k4 * 4];
      acc[i] += cv.x * w.x + cv.y * w.y + cv.z * w.z + cv.w * w.w;
    }
  }
  int xy = t & 1;
  for (int i = 0; i < HEAD_QI; i++) {
    int bn = bn0 + i;
    const float* bd = boxd + (size_t)bn * 12;
    float off = acc[i] + offb[t];
    float ctr = xy ? bd[5] : bd[4];
    float wh = xy ? bd[7] : bd[6];
    float sxy = ctr + off * wh;
    out_offset[(size_t)bn * 256 + t] = off;
    out_sxy[(size_t)bn * 256 + t] = sxy;
    sxy_ws[(size_t)bn * 256 + t] = sxy;
  }
  if (t < 128) {
    float acs[HEAD_QI] = {0.f, 0.f, 0.f, 0.f};
    const float4* sw4 = (const float4*)(scW + (size_t)t * C_);
    for (int k4 = 0; k4 < C_ / 4; k4++) {
      float4 w = sw4[k4];
      for (int i = 0; i < HEAD_QI; i++) {
        float4 cv = *(const float4*)&qs[i][k4 * 4];
        acs[i] += cv.x * w.x + cv.y * w.y + cv.z * w.z + cv.w * w.w;
      }
    }
    for (int i = 0; i < HEAD_QI; i++) {
      int bn = bn0 + i;
      const float* bd = boxd + (size_t)bn * 12;
      float sl = acs[i] + scb[t];
      float sz = sl + bd[8];
      out_sl[(size_t)bn * 128 + t] = sl;
      out_sz[(size_t)bn * 128 + t] = sz;
      float lvl = sz - 3.0f;
      float e0 = __expf(-0.5f * lvl * lvl);
      float d1 = lvl - 1.f, d2 = lvl - 2.f, d3 = lvl - 3.f;
      float e1 = __expf(-0.5f * d1 * d1);
      float e2 = __expf(-0.5f * d2 * d2);
      float e3 = __expf(-0.5f * d3 * d3);
      float inv = 1.0f / (e0 + e1 + e2 + e3);
      float* zw = zw_ws + ((size_t)bn * 128 + t) * 4;
      zw[0] = e0 * inv; zw[1] = e1 * inv; zw[2] = e2 * inv; zw[3] = e3 * inv;
    }
  }
}

// ---------------------------------------------------------------------------
// K6: multi-level bilinear group sampling. One wave per point (lane=channel).
template <bool TRANSPOSED>
__global__ __launch_bounds__(256) void sample_kernel(
    const float* __restrict__ f0, const float* __restrict__ f1,
    const float* __restrict__ f2, const float* __restrict__ f3,
    const float* __restrict__ sxy, const float* __restrict__ zw_ws,
    float* __restrict__ out) {
  int t = threadIdx.x;
  int wv = t >> 6;
  int lane = t & 63;
  int pt = blockIdx.x * 4 + wv; // pt = bn*128 + p*4 + g
  int g = pt & 3;
  int p = (pt >> 2) & 31;
  int bn = pt >> 7;
  int b = bn / N_;

  float sx = sxy[(size_t)pt * 2];
  float sy = sxy[(size_t)pt * 2 + 1];
  const float* zw = zw_ws + (size_t)pt * 4;
  const float* feats[4] = {f0, f1, f2, f3};
  const float inv_stride[4] = {0.125f, 0.0625f, 0.03125f, 0.015625f};
  float acc = 0.f;
#pragma unroll
  for (int l = 0; l < 4; l++) {
    float wl = zw[l];
    int W = LVL_W[l];
    float px = sx * inv_stride[l] - 0.5f;
    float py = sy * inv_stride[l] - 0.5f;
    float x0f = floorf(px), y0f = floorf(py);
    float fx = px - x0f, fy = py - y0f;
    int x0 = (int)x0f, y0 = (int)y0f;
#pragma unroll
    for (int dy = 0; dy < 2; dy++) {
#pragma unroll
      for (int dx = 0; dx < 2; dx++) {
        int xi = x0 + dx, yi = y0 + dy;
        if (xi >= 0 && xi < W && yi >= 0 && yi < W) {
          float wgt = (dx ? fx : 1.f - fx) * (dy ? fy : 1.f - fy);
          float v;
          if (TRANSPOSED)
            v = feats[l][((size_t)b * W * W + (size_t)yi * W + xi) * C_ + g * CG_ + lane];
          else
            v = feats[l][(((size_t)b * C_ + g * CG_ + lane) * W + yi) * W + xi];
          acc += wgt * wl * v;
        }
      }
    }
  }
  out[(size_t)bn * 8192 + g * 2048 + p * 64 + lane] = acc;
}

// ---------------------------------------------------------------------------
extern "C" void kernel_launch(void* const* d_in, const int* in_sizes, int n_in,
                              void* d_out, int out_size, void* d_ws, size_t ws_size,
                              hipStream_t stream) {
  (void)in_sizes; (void)n_in; (void)out_size;
  const float* feat[4] = {(const float*)d_in[0], (const float*)d_in[1],
                          (const float*)d_in[2], (const float*)d_in[3]};
  const float* query_content = (const float*)d_in[4];
  const float* query_box = (const float*)d_in[5];
  const float* Wq = (const float*)d_in[10]; const float* bq = (const float*)d_in[11];
  const float* Wk = (const float*)d_in[12]; const float* bk = (const float*)d_in[13];
  const float* Wv = (const float*)d_in[14]; const float* bv = (const float*)d_in[15];
  const float* Wo = (const float*)d_in[16]; const float* bo = (const float*)d_in[17];
  const float* ln_g = (const float*)d_in[18]; const float* ln_b = (const float*)d_in[19];
  const float* offW = (const float*)d_in[20]; const float* offb = (const float*)d_in[21];
  const float* scW = (const float*)d_in[22]; const float* scb = (const float*)d_in[23];
  const float* iof_tau = (const float*)d_in[24];

  float* out = (float*)d_out;
  float* ws = (float*)d_ws;

  // output offsets (floats)
  const size_t O_FEATS = 0;            // 16,384,000
  const size_t O_SUBXY = 16384000;     //    512,000
  const size_t O_SUBZ = 16896000;      //  1,024,000
  const size_t O_SUBV = 17920000;      // 16,384,000
  const size_t O_QC = 34304000;        //    512,000
  const size_t O_SXY = 34816000;       //    512,000
  const size_t O_OFF = 35328000;       //    512,000
  const size_t O_SZ = 35840000;        //    256,000
  const size_t O_SL = 36096000;        //    256,000

  // workspace layout (floats)
  const size_t o_x = 0;                          // 512,000
  const size_t o_boxd = o_x + 512000;            //  24,000
  const size_t o_q = o_boxd + 24000;             // 512,000
  const size_t o_kT = o_q + 512000;              // 512,000
  const size_t o_vT = o_kT + 512000;             // 512,000
  const size_t o_ctx = o_vT + 512000;            // 512,000
  const size_t o_qc = o_ctx + 512000;            // 512,000
  const size_t o_zw = o_qc + 512000;             // 1,024,000
  const size_t o_sxy = o_zw + 1024000;           // 512,000
  const size_t o_ft = o_sxy + 512000;            // 22,282,240 (transposed feats)
  const size_t ft_sz[4] = {16777216, 4194304, 1048576, 262144};
  const size_t need_T = (o_ft + ft_sz[0] + ft_sz[1] + ft_sz[2] + ft_sz[3]) * sizeof(float);
  const bool useT = ws_size >= need_T;

  // passthrough outputs
  hipMemcpyAsync(out + O_SUBXY, d_in[6], 512000 * sizeof(float), hipMemcpyDeviceToDevice, stream);
  hipMemcpyAsync(out + O_SUBZ, d_in[7], 1024000 * sizeof(float), hipMemcpyDeviceToDevice, stream);
  hipMemcpyAsync(out + O_SUBV, d_in[8], 16384000 * sizeof(float), hipMemcpyDeviceToDevice, stream);

  float* ftb[4] = {ws + o_ft,
                   ws + o_ft + ft_sz[0],
                   ws + o_ft + ft_sz[0] + ft_sz[1],
                   ws + o_ft + ft_sz[0] + ft_sz[1] + ft_sz[2]};
  if (useT) {
    const int npix[4] = {16384, 4096, 1024, 256};
    for (int l = 0; l < 4; l++) {
      dim3 g(npix[l] / 64, C_ / 64, B_);
      transpose_feat<<<g, 256, 0, stream>>>(feat[l], ftb[l], npix[l]);
    }
  }

  prep_kernel<<<BN_, 256, 0, stream>>>(query_content, query_box, ws + o_x, ws + o_boxd);
  qkv_kernel<<<BN_ / QKV_QI, 256, 0, stream>>>(ws + o_x, Wq, bq, Wk, bk, Wv, bv,
                                               ws + o_q, ws + o_kT, ws + o_vT);
  attn_kernel<<<BN_ / ATT_QI, 256, 0, stream>>>(ws + o_q, ws + o_kT, ws + o_vT,
                                                ws + o_boxd, iof_tau, ws + o_ctx);
  projln_kernel<<<BN_ / PROJ_QI, 256, 0, stream>>>(ws + o_ctx, ws + o_x, Wo, bo, ln_g, ln_b,
                                                   ws + o_qc, out + O_QC);
  head_kernel<<<BN_ / HEAD_QI, 256, 0, stream>>>(ws + o_qc, ws + o_boxd, offW, offb, scW, scb,
                                                 out + O_OFF, out + O_SXY, out + O_SZ, out + O_SL,
                                                 ws + o_sxy, ws + o_zw);
  const int npoints = BN_ * P_ * G_; // 256,000
  if (useT) {
    sample_kernel<true><<<npoints / 4, 256, 0, stream>>>(ftb[0], ftb[1], ftb[2], ftb[3],
                                                         ws + o_sxy, ws + o_zw, out + O_FEATS);
  } else {
    sample_kernel<false><<<npoints / 4, 256, 0, stream>>>(feat[0], feat[1], feat[2], feat[3],
                                                          ws + o_sxy, ws + o_zw, out + O_FEATS);
  }
}

// Round 2
// 306.331 us; speedup vs baseline: 1.5719x; 1.5719x over previous
//
#include <hip/hip_runtime.h>
#include <cstdint>
#include <cstddef>

// Problem constants (match reference setup_inputs)
#define B_ 4
#define N_ 500
#define C_ 256
#define NH_ 8
#define DH_ 32
#define P_ 32
#define G_ 4
#define CG_ 64
#define BN_ (B_*N_)

__constant__ const int LVL_W[4] = {128, 64, 32, 16};

// ---------------------------------------------------------------------------
// K0: transpose (B,C,H,W) -> (B,H*W,C) for coalesced channel-group gathers
__global__ __launch_bounds__(256) void transpose_feat(const float* __restrict__ src,
                                                      float* __restrict__ dst, int npix) {
  __shared__ float tile[64][65];
  int b = blockIdx.z;
  int c0 = blockIdx.y * 64;
  int p0 = blockIdx.x * 64;
  int t = threadIdx.x;
  for (int i = 0; i < 16; i++) {
    int cl = i * 4 + (t >> 6);
    int pl = t & 63;
    tile[cl][pl] = src[((size_t)b * C_ + (c0 + cl)) * npix + (p0 + pl)];
  }
  __syncthreads();
  for (int i = 0; i < 16; i++) {
    int pl = i * 4 + (t >> 6);
    int cl = t & 63;
    dst[((size_t)b * npix + (p0 + pl)) * C_ + (c0 + cl)] = tile[cl][pl];
  }
}

// ---------------------------------------------------------------------------
// K1: per-query prep: positional embedding + x = content + pe, box decode
__global__ __launch_bounds__(256) void prep_kernel(const float* __restrict__ qcontent,
                                                   const float* __restrict__ qbox,
                                                   float* __restrict__ x,
                                                   float* __restrict__ boxd) {
  int bn = blockIdx.x;
  int t = threadIdx.x;
  const float* qb = qbox + (size_t)bn * 4;
  float cx = qb[0], cy = qb[1], z = qb[2], r = qb[3];

  int d = t >> 6;
  int j = (t >> 1) & 31;
  float token = (d == 0) ? cx * 0.001f : (d == 1) ? cy * 0.001f : (d == 2) ? z : r;
  float tj = exp2f((float)j * 0.41524136f); // log2(10000)/32
  float val = token / tj;
  float pe = (t & 1) ? cosf(val) : sinf(val);
  x[(size_t)bn * C_ + t] = qcontent[(size_t)bn * C_ + t] + pe;

  if (t == 0) {
    float scale = exp2f(z);
    float w = scale * exp2f(-0.5f * r);
    float h = scale * exp2f(0.5f * r);
    float* bd = boxd + (size_t)bn * 12;
    float x1 = cx - 0.5f * w, y1 = cy - 0.5f * h, x2 = cx + 0.5f * w, y2 = cy + 0.5f * h;
    bd[0] = x1; bd[1] = y1; bd[2] = x2; bd[3] = y2;
    bd[4] = cx; bd[5] = cy; bd[6] = w; bd[7] = h; bd[8] = z;
    float area = fmaxf(x2 - x1, 0.f) * fmaxf(y2 - y1, 0.f);
    bd[9] = fmaxf(area, 1e-7f);
  }
}

// ---------------------------------------------------------------------------
// K2: QKV projections. 8 queries per block for W reuse. k transposed, v row-major.
#define QKV_QI 8
__global__ __launch_bounds__(256) void qkv_kernel(const float* __restrict__ x,
    const float* __restrict__ Wq, const float* __restrict__ bq,
    const float* __restrict__ Wk, const float* __restrict__ bk,
    const float* __restrict__ Wv, const float* __restrict__ bv,
    float* __restrict__ q, float* __restrict__ kT, float* __restrict__ v) {
  __shared__ float xs[QKV_QI][C_];
  int blk = blockIdx.x;
  int t = threadIdx.x;
  int bn0 = blk * QKV_QI;
  for (int i = 0; i < QKV_QI; i++) xs[i][t] = x[(size_t)(bn0 + i) * C_ + t];
  __syncthreads();
  float accq[QKV_QI], acck[QKV_QI], accv[QKV_QI];
  for (int i = 0; i < QKV_QI; i++) { accq[i] = 0.f; acck[i] = 0.f; accv[i] = 0.f; }
  const float4* wq4 = (const float4*)(Wq + (size_t)t * C_);
  const float4* wk4 = (const float4*)(Wk + (size_t)t * C_);
  const float4* wv4 = (const float4*)(Wv + (size_t)t * C_);
  for (int k4 = 0; k4 < C_ / 4; k4++) {
    float4 wq = wq4[k4], wk = wk4[k4], wv = wv4[k4];
    for (int i = 0; i < QKV_QI; i++) {
      float4 xv = *(const float4*)&xs[i][k4 * 4];
      accq[i] += xv.x * wq.x + xv.y * wq.y + xv.z * wq.z + xv.w * wq.w;
      acck[i] += xv.x * wk.x + xv.y * wk.y + xv.z * wk.z + xv.w * wk.w;
      accv[i] += xv.x * wv.x + xv.y * wv.y + xv.z * wv.z + xv.w * wv.w;
    }
  }
  for (int i = 0; i < QKV_QI; i++) {
    int bn = bn0 + i;
    int b = bn / N_;
    int n = bn % N_;
    q[(size_t)bn * C_ + t] = accq[i] + bq[t];
    kT[((size_t)b * C_ + t) * N_ + n] = acck[i] + bk[t];
    v[(size_t)bn * C_ + t] = accv[i] + bv[t];
  }
}

// ---------------------------------------------------------------------------
// K3: attention with IoF bias. 2 queries per block.
// QK^T uses kT (coalesced over m). PV uses row-major v: m split across 4 waves,
// float4 channel loads (fully coalesced), LDS partial reduce.
#define ATT_QI 2
__global__ __launch_bounds__(256) void attn_kernel(
    const float* __restrict__ q, const float* __restrict__ kT, const float* __restrict__ v,
    const float* __restrict__ boxd, const float* __restrict__ tau_p,
    float* __restrict__ ctx) {
  __shared__ float p[ATT_QI][NH_][N_];
  __shared__ float bias[ATT_QI][N_];
  __shared__ float qs[ATT_QI][C_];
  __shared__ float red[ATT_QI * NH_];
  __shared__ float part[4][ATT_QI][C_];
  int blk = blockIdx.x;
  int b = blk / (N_ / ATT_QI);
  int n0 = (blk % (N_ / ATT_QI)) * ATT_QI;
  int t = threadIdx.x;
  for (int i = 0; i < ATT_QI; i++) qs[i][t] = q[((size_t)b * N_ + n0 + i) * C_ + t];
  for (int i = 0; i < ATT_QI; i++) {
    const float* bdn = boxd + ((size_t)b * N_ + n0 + i) * 12;
    float nx1 = bdn[0], ny1 = bdn[1], nx2 = bdn[2], ny2 = bdn[3];
    float inv_area = 1.0f / bdn[9];
    for (int m = t; m < N_; m += 256) {
      const float* bdm = boxd + ((size_t)b * N_ + m) * 12;
      float iw = fmaxf(fminf(nx2, bdm[2]) - fmaxf(nx1, bdm[0]), 0.f);
      float ih = fmaxf(fminf(ny2, bdm[3]) - fmaxf(ny1, bdm[1]), 0.f);
      bias[i][m] = logf(iw * ih * inv_area + 1e-7f);
    }
  }
  __syncthreads();
  const float scl = 0.17677669529663687f; // 32^-0.5
  for (int h = 0; h < NH_; h++) {
    float tau = tau_p[h];
    for (int mb = 0; mb < N_; mb += 256) {
      int m = mb + t;
      if (m < N_) {
        const float* kcol = kT + ((size_t)b * C_ + h * DH_) * N_ + m;
        float s0 = 0.f, s1 = 0.f;
        for (int d = 0; d < DH_; d++) {
          float kv = kcol[(size_t)d * N_];
          s0 += qs[0][h * DH_ + d] * kv;
          s1 += qs[1][h * DH_ + d] * kv;
        }
        p[0][h][m] = s0 * scl + bias[0][m] * tau;
        p[1][h][m] = s1 * scl + bias[1][m] * tau;
      }
    }
  }
  __syncthreads();
  {
    // softmax: 16 (qi,h) pairs, 16 threads per pair
    int pair = t >> 4;
    int j = t & 15;
    int qi = pair >> 3;
    int h = pair & 7;
    float mx = -1e30f;
    for (int m = j; m < N_; m += 16) mx = fmaxf(mx, p[qi][h][m]);
    for (int off = 8; off >= 1; off >>= 1) mx = fmaxf(mx, __shfl_xor(mx, off, 64));
    float sum = 0.f;
    for (int m = j; m < N_; m += 16) {
      float e = __expf(p[qi][h][m] - mx);
      p[qi][h][m] = e;
      sum += e;
    }
    for (int off = 8; off >= 1; off >>= 1) sum += __shfl_xor(sum, off, 64);
    if (j == 0) red[pair] = 1.0f / sum;
  }
  __syncthreads();
  {
    // PV: wave mq handles m in [mq*125, mq*125+125); lane covers 4 channels.
    int mq = t >> 6;
    int lane = t & 63;
    int c0 = lane * 4;
    int h = lane >> 3; // c0>>5
    float4 a0 = {0.f, 0.f, 0.f, 0.f}, a1 = {0.f, 0.f, 0.f, 0.f};
    int m0 = mq * 125;
    for (int m = m0; m < m0 + 125; m++) {
      float4 vv = *(const float4*)&v[((size_t)b * N_ + m) * C_ + c0];
      float p0 = p[0][h][m], p1 = p[1][h][m];
      a0.x += p0 * vv.x; a0.y += p0 * vv.y; a0.z += p0 * vv.z; a0.w += p0 * vv.w;
      a1.x += p1 * vv.x; a1.y += p1 * vv.y; a1.z += p1 * vv.z; a1.w += p1 * vv.w;
    }
    *(float4*)&part[mq][0][c0] = a0;
    *(float4*)&part[mq][1][c0] = a1;
  }
  __syncthreads();
  {
    int hh = t >> 5;
    float r0 = (part[0][0][t] + part[1][0][t] + part[2][0][t] + part[3][0][t]) * red[0 * 8 + hh];
    float r1 = (part[0][1][t] + part[1][1][t] + part[2][1][t] + part[3][1][t]) * red[1 * 8 + hh];
    ctx[((size_t)b * N_ + n0 + 0) * C_ + t] = r0;
    ctx[((size_t)b * N_ + n0 + 1) * C_ + t] = r1;
  }
}

// ---------------------------------------------------------------------------
// K4: output projection + residual + layernorm. 4 queries per block.
#define PROJ_QI 4
__global__ __launch_bounds__(256) void projln_kernel(const float* __restrict__ ctx,
    const float* __restrict__ x,
    const float* __restrict__ Wo, const float* __restrict__ bo,
    const float* __restrict__ ln_g, const float* __restrict__ ln_b,
    float* __restrict__ qc_ws, float* __restrict__ qc_out) {
  __shared__ float cs[PROJ_QI][C_];
  __shared__ float redbuf[PROJ_QI][8];
  int blk = blockIdx.x;
  int t = threadIdx.x;
  int bn0 = blk * PROJ_QI;
  for (int i = 0; i < PROJ_QI; i++) cs[i][t] = ctx[(size_t)(bn0 + i) * C_ + t];
  __syncthreads();
  float acc[PROJ_QI] = {0.f, 0.f, 0.f, 0.f};
  const float4* w4 = (const float4*)(Wo + (size_t)t * C_);
  for (int k4 = 0; k4 < C_ / 4; k4++) {
    float4 w = w4[k4];
    for (int i = 0; i < PROJ_QI; i++) {
      float4 cv = *(const float4*)&cs[i][k4 * 4];
      acc[i] += cv.x * w.x + cv.y * w.y + cv.z * w.z + cv.w * w.w;
    }
  }
  float y[PROJ_QI];
  int wave = t >> 6, lane = t & 63;
  for (int i = 0; i < PROJ_QI; i++) {
    y[i] = x[(size_t)(bn0 + i) * C_ + t] + acc[i] + bo[t];
    float s1 = y[i], s2 = y[i] * y[i];
    for (int off = 32; off >= 1; off >>= 1) {
      s1 += __shfl_xor(s1, off, 64);
      s2 += __shfl_xor(s2, off, 64);
    }
    if (lane == 0) { redbuf[i][wave] = s1; redbuf[i][wave + 4] = s2; }
  }
  __syncthreads();
  for (int i = 0; i < PROJ_QI; i++) {
    float s1 = redbuf[i][0] + redbuf[i][1] + redbuf[i][2] + redbuf[i][3];
    float s2 = redbuf[i][4] + redbuf[i][5] + redbuf[i][6] + redbuf[i][7];
    float mu = s1 * (1.0f / C_);
    float var = s2 * (1.0f / C_) - mu * mu;
    float inv = rsqrtf(var + 1e-5f);
    float o = (y[i] - mu) * inv * ln_g[t] + ln_b[t];
    qc_ws[(size_t)(bn0 + i) * C_ + t] = o;
    qc_out[(size_t)(bn0 + i) * C_ + t] = o;
  }
}

// ---------------------------------------------------------------------------
// K5: offset/scale heads + sample_xy / sample_z / level softmax weights
#define HEAD_QI 4
__global__ __launch_bounds__(256) void head_kernel(const float* __restrict__ qc,
    const float* __restrict__ boxd,
    const float* __restrict__ offW, const float* __restrict__ offb,
    const float* __restrict__ scW, const float* __restrict__ scb,
    float* __restrict__ out_offset, float* __restrict__ out_sxy,
    float* __restrict__ out_sz, float* __restrict__ out_sl,
    float* __restrict__ sxy_ws, float* __restrict__ zw_ws) {
  __shared__ float qs[HEAD_QI][C_];
  int blk = blockIdx.x;
  int t = threadIdx.x;
  int bn0 = blk * HEAD_QI;
  for (int i = 0; i < HEAD_QI; i++) qs[i][t] = qc[(size_t)(bn0 + i) * C_ + t];
  __syncthreads();
  float acc[HEAD_QI] = {0.f, 0.f, 0.f, 0.f};
  const float4* w4 = (const float4*)(offW + (size_t)t * C_);
  for (int k4 = 0; k4 < C_ / 4; k4++) {
    float4 w = w4[k4];
    for (int i = 0; i < HEAD_QI; i++) {
      float4 cv = *(const float4*)&qs[i][k4 * 4];
      acc[i] += cv.x * w.x + cv.y * w.y + cv.z * w.z + cv.w * w.w;
    }
  }
  int xy = t & 1;
  for (int i = 0; i < HEAD_QI; i++) {
    int bn = bn0 + i;
    const float* bd = boxd + (size_t)bn * 12;
    float off = acc[i] + offb[t];
    float ctr = xy ? bd[5] : bd[4];
    float wh = xy ? bd[7] : bd[6];
    float sxy = ctr + off * wh;
    out_offset[(size_t)bn * 256 + t] = off;
    out_sxy[(size_t)bn * 256 + t] = sxy;
    sxy_ws[(size_t)bn * 256 + t] = sxy;
  }
  if (t < 128) {
    float acs[HEAD_QI] = {0.f, 0.f, 0.f, 0.f};
    const float4* sw4 = (const float4*)(scW + (size_t)t * C_);
    for (int k4 = 0; k4 < C_ / 4; k4++) {
      float4 w = sw4[k4];
      for (int i = 0; i < HEAD_QI; i++) {
        float4 cv = *(const float4*)&qs[i][k4 * 4];
        acs[i] += cv.x * w.x + cv.y * w.y + cv.z * w.z + cv.w * w.w;
      }
    }
    for (int i = 0; i < HEAD_QI; i++) {
      int bn = bn0 + i;
      const float* bd = boxd + (size_t)bn * 12;
      float sl = acs[i] + scb[t];
      float sz = sl + bd[8];
      out_sl[(size_t)bn * 128 + t] = sl;
      out_sz[(size_t)bn * 128 + t] = sz;
      float lvl = sz - 3.0f;
      float e0 = __expf(-0.5f * lvl * lvl);
      float d1 = lvl - 1.f, d2 = lvl - 2.f, d3 = lvl - 3.f;
      float e1 = __expf(-0.5f * d1 * d1);
      float e2 = __expf(-0.5f * d2 * d2);
      float e3 = __expf(-0.5f * d3 * d3);
      float inv = 1.0f / (e0 + e1 + e2 + e3);
      float* zw = zw_ws + ((size_t)bn * 128 + t) * 4;
      zw[0] = e0 * inv; zw[1] = e1 * inv; zw[2] = e2 * inv; zw[3] = e3 * inv;
    }
  }
}

// ---------------------------------------------------------------------------
// K6 v2: multi-level bilinear group sampling on transposed feats.
// 4 (point,group) per wave; 16 lanes per point; float4 per lane (4 channels).
// No branches: clamped indices + zeroed weights.
__global__ __launch_bounds__(256) void sample_kernel_v2(
    const float* __restrict__ f0, const float* __restrict__ f1,
    const float* __restrict__ f2, const float* __restrict__ f3,
    const float* __restrict__ sxy, const float* __restrict__ zw_ws,
    float* __restrict__ out) {
  int t = threadIdx.x;
  int wv = t >> 6;
  int lane = t & 63;
  int sub = lane >> 4;   // point within wave
  int c4 = lane & 15;    // channel quad within group
  int pt = blockIdx.x * 16 + wv * 4 + sub; // pt = bn*128 + p*4 + g
  int g = pt & 3;
  int p = (pt >> 2) & 31;
  int bn = pt >> 7;
  int b = bn / N_;

  float sx = sxy[(size_t)pt * 2];
  float sy = sxy[(size_t)pt * 2 + 1];
  const float* zw = zw_ws + (size_t)pt * 4;
  const float* feats[4] = {f0, f1, f2, f3};
  const float inv_stride[4] = {0.125f, 0.0625f, 0.03125f, 0.015625f};
  float4 acc = {0.f, 0.f, 0.f, 0.f};
#pragma unroll
  for (int l = 0; l < 4; l++) {
    float wl = zw[l];
    int W = LVL_W[l];
    float px = sx * inv_stride[l] - 0.5f;
    float py = sy * inv_stride[l] - 0.5f;
    float x0f = floorf(px), y0f = floorf(py);
    float fx = px - x0f, fy = py - y0f;
    int x0 = (int)x0f, y0 = (int)y0f;
    const float* fb = feats[l] + (size_t)b * W * W * C_ + g * CG_ + c4 * 4;
#pragma unroll
    for (int dy = 0; dy < 2; dy++) {
#pragma unroll
      for (int dx = 0; dx < 2; dx++) {
        int xi = x0 + dx, yi = y0 + dy;
        float valid = (xi >= 0 && xi < W && yi >= 0 && yi < W) ? 1.f : 0.f;
        int xc = min(max(xi, 0), W - 1);
        int yc = min(max(yi, 0), W - 1);
        float wgt = (dx ? fx : 1.f - fx) * (dy ? fy : 1.f - fy) * valid * wl;
        float4 vv = *(const float4*)&fb[((size_t)yc * W + xc) * C_];
        acc.x += wgt * vv.x; acc.y += wgt * vv.y; acc.z += wgt * vv.z; acc.w += wgt * vv.w;
      }
    }
  }
  *(float4*)&out[(size_t)bn * 8192 + g * 2048 + p * 64 + c4 * 4] = acc;
}

// Fallback: native-layout scalar sampler (used only if ws too small to transpose)
__global__ __launch_bounds__(256) void sample_kernel_native(
    const float* __restrict__ f0, const float* __restrict__ f1,
    const float* __restrict__ f2, const float* __restrict__ f3,
    const float* __restrict__ sxy, const float* __restrict__ zw_ws,
    float* __restrict__ out) {
  int t = threadIdx.x;
  int wv = t >> 6;
  int lane = t & 63;
  int pt = blockIdx.x * 4 + wv;
  int g = pt & 3;
  int p = (pt >> 2) & 31;
  int bn = pt >> 7;
  int b = bn / N_;
  float sx = sxy[(size_t)pt * 2];
  float sy = sxy[(size_t)pt * 2 + 1];
  const float* zw = zw_ws + (size_t)pt * 4;
  const float* feats[4] = {f0, f1, f2, f3};
  const float inv_stride[4] = {0.125f, 0.0625f, 0.03125f, 0.015625f};
  float acc = 0.f;
#pragma unroll
  for (int l = 0; l < 4; l++) {
    float wl = zw[l];
    int W = LVL_W[l];
    float px = sx * inv_stride[l] - 0.5f;
    float py = sy * inv_stride[l] - 0.5f;
    float x0f = floorf(px), y0f = floorf(py);
    float fx = px - x0f, fy = py - y0f;
    int x0 = (int)x0f, y0 = (int)y0f;
#pragma unroll
    for (int dy = 0; dy < 2; dy++) {
#pragma unroll
      for (int dx = 0; dx < 2; dx++) {
        int xi = x0 + dx, yi = y0 + dy;
        if (xi >= 0 && xi < W && yi >= 0 && yi < W) {
          float wgt = (dx ? fx : 1.f - fx) * (dy ? fy : 1.f - fy);
          float v = feats[l][(((size_t)b * C_ + g * CG_ + lane) * W + yi) * W + xi];
          acc += wgt * wl * v;
        }
      }
    }
  }
  out[(size_t)bn * 8192 + g * 2048 + p * 64 + lane] = acc;
}

// ---------------------------------------------------------------------------
extern "C" void kernel_launch(void* const* d_in, const int* in_sizes, int n_in,
                              void* d_out, int out_size, void* d_ws, size_t ws_size,
                              hipStream_t stream) {
  (void)in_sizes; (void)n_in; (void)out_size;
  const float* feat[4] = {(const float*)d_in[0], (const float*)d_in[1],
                          (const float*)d_in[2], (const float*)d_in[3]};
  const float* query_content = (const float*)d_in[4];
  const float* query_box = (const float*)d_in[5];
  const float* Wq = (const float*)d_in[10]; const float* bq = (const float*)d_in[11];
  const float* Wk = (const float*)d_in[12]; const float* bk = (const float*)d_in[13];
  const float* Wv = (const float*)d_in[14]; const float* bv = (const float*)d_in[15];
  const float* Wo = (const float*)d_in[16]; const float* bo = (const float*)d_in[17];
  const float* ln_g = (const float*)d_in[18]; const float* ln_b = (const float*)d_in[19];
  const float* offW = (const float*)d_in[20]; const float* offb = (const float*)d_in[21];
  const float* scW = (const float*)d_in[22]; const float* scb = (const float*)d_in[23];
  const float* iof_tau = (const float*)d_in[24];

  float* out = (float*)d_out;
  float* ws = (float*)d_ws;

  // output offsets (floats)
  const size_t O_FEATS = 0;            // 16,384,000
  const size_t O_SUBXY = 16384000;     //    512,000
  const size_t O_SUBZ = 16896000;      //  1,024,000
  const size_t O_SUBV = 17920000;      // 16,384,000
  const size_t O_QC = 34304000;        //    512,000
  const size_t O_SXY = 34816000;       //    512,000
  const size_t O_OFF = 35328000;       //    512,000
  const size_t O_SZ = 35840000;        //    256,000
  const size_t O_SL = 36096000;        //    256,000

  // workspace layout (floats)
  const size_t o_x = 0;                          // 512,000
  const size_t o_boxd = o_x + 512000;            //  24,000
  const size_t o_q = o_boxd + 24000;             // 512,000
  const size_t o_kT = o_q + 512000;              // 512,000
  const size_t o_v = o_kT + 512000;              // 512,000
  const size_t o_ctx = o_v + 512000;             // 512,000
  const size_t o_qc = o_ctx + 512000;            // 512,000
  const size_t o_zw = o_qc + 512000;             // 1,024,000
  const size_t o_sxy = o_zw + 1024000;           // 512,000
  const size_t o_ft = o_sxy + 512000;            // 22,282,240 (transposed feats)
  const size_t ft_sz[4] = {16777216, 4194304, 1048576, 262144};
  const size_t need_T = (o_ft + ft_sz[0] + ft_sz[1] + ft_sz[2] + ft_sz[3]) * sizeof(float);
  const bool useT = ws_size >= need_T;

  // passthrough outputs
  hipMemcpyAsync(out + O_SUBXY, d_in[6], 512000 * sizeof(float), hipMemcpyDeviceToDevice, stream);
  hipMemcpyAsync(out + O_SUBZ, d_in[7], 1024000 * sizeof(float), hipMemcpyDeviceToDevice, stream);
  hipMemcpyAsync(out + O_SUBV, d_in[8], 16384000 * sizeof(float), hipMemcpyDeviceToDevice, stream);

  float* ftb[4] = {ws + o_ft,
                   ws + o_ft + ft_sz[0],
                   ws + o_ft + ft_sz[0] + ft_sz[1],
                   ws + o_ft + ft_sz[0] + ft_sz[1] + ft_sz[2]};
  if (useT) {
    const int npix[4] = {16384, 4096, 1024, 256};
    for (int l = 0; l < 4; l++) {
      dim3 g(npix[l] / 64, C_ / 64, B_);
      transpose_feat<<<g, 256, 0, stream>>>(feat[l], ftb[l], npix[l]);
    }
  }

  prep_kernel<<<BN_, 256, 0, stream>>>(query_content, query_box, ws + o_x, ws + o_boxd);
  qkv_kernel<<<BN_ / QKV_QI, 256, 0, stream>>>(ws + o_x, Wq, bq, Wk, bk, Wv, bv,
                                               ws + o_q, ws + o_kT, ws + o_v);
  attn_kernel<<<BN_ / ATT_QI, 256, 0, stream>>>(ws + o_q, ws + o_kT, ws + o_v,
                                                ws + o_boxd, iof_tau, ws + o_ctx);
  projln_kernel<<<BN_ / PROJ_QI, 256, 0, stream>>>(ws + o_ctx, ws + o_x, Wo, bo, ln_g, ln_b,
                                                   ws + o_qc, out + O_QC);
  head_kernel<<<BN_ / HEAD_QI, 256, 0, stream>>>(ws + o_qc, ws + o_boxd, offW, offb, scW, scb,
                                                 out + O_OFF, out + O_SXY, out + O_SZ, out + O_SL,
                                                 ws + o_sxy, ws + o_zw);
  const int npoints = BN_ * P_ * G_; // 256,000
  if (useT) {
    sample_kernel_v2<<<npoints / 16, 256, 0, stream>>>(ftb[0], ftb[1], ftb[2], ftb[3],
                                                       ws + o_sxy, ws + o_zw, out + O_FEATS);
  } else {
    sample_kernel_native<<<npoints / 4, 256, 0, stream>>>(feat[0], feat[1], feat[2], feat[3],
                                                          ws + o_sxy, ws + o_zw, out + O_FEATS);
  }
}